// Round 9
// baseline (217.512 us; speedup 1.0000x reference)
//
#include <hip/hip_runtime.h>
#include <hip/hip_bf16.h>

#define BATCH 4096
#define SEQ 10
#define DIM 1024
#define TWOD 2048
#define HID 512

typedef __attribute__((ext_vector_type(8))) short bf16x8;
typedef __attribute__((ext_vector_type(8))) unsigned short ushort8_t;
typedef __attribute__((ext_vector_type(4))) float f32x4;

// ---------------- workspace layout (bytes) ----------------
#define OFF_ABF   0ull                 // bf16 [8192][2048]   32 MB
#define OFF_OCB   (32ull << 20)        // bf16 [4096][2048]   16 MB
#define OFF_WGT   (48ull << 20)        // bf16 [1024][2048]    4 MB
#define OFF_WFDT  (52ull << 20)        // bf16 [512][2048]     2 MB
#define OFF_LOG   (54ull << 20)        // f32  [4096]
#define OFF_AROW  (62ull << 20)        // f32  [4096*16]
#define OFF_STATS (OFF_AROW + 4096ull * 16 * 4)
#define OFF_X2H   (64ull << 20)        // bf16 [4096][10][1024] 80 MB (optional)
#define WS_NEED_X2H (144ull << 20)

#define GLOAD_LDS16(g, l)                                                     \
  __builtin_amdgcn_global_load_lds(                                           \
      (const __attribute__((address_space(1))) unsigned int*)(g),             \
      (__attribute__((address_space(3))) unsigned int*)(l), 16, 0, 0)

// XOR-swizzle over the 4 16B k-slots of a 64B LDS row.
#define SW(r) (((r) + ((r) >> 2)) & 3)

static __device__ inline void store_bf4(__hip_bfloat16* p, float4 v) {
  ushort4 u;
  __hip_bfloat16 a = __float2bfloat16(v.x), b = __float2bfloat16(v.y),
                 c = __float2bfloat16(v.z), d = __float2bfloat16(v.w);
  u.x = *(unsigned short*)&a; u.y = *(unsigned short*)&b;
  u.z = *(unsigned short*)&c; u.w = *(unsigned short*)&d;
  *(ushort4*)p = u;
}

static __device__ inline float bf2f(unsigned short u) {
  return __uint_as_float(((unsigned)u) << 16);
}

// P1: block per batch, 4 waves; each wave OWNS 5 dot products over full rows.
//  wave0: px[0..4]  loads X1[0..4], X2[9]
//  wave1: px[5..9]  loads X1[5..9], X2[9]
//  wave2: py[0..4]  loads X2[0..4], X1[9]
//  wave3: py[5..9]  loads X2[5..9], X1[9]
// NEW: waves 2/3 dump their register-held X2 rows as bf16 into x2h so the
// apply pass reads half the bytes.
__global__ __launch_bounds__(256) void k_scores(
    const float* __restrict__ X1, const float* __restrict__ X2,
    __hip_bfloat16* __restrict__ abf, float* __restrict__ arow,
    float* __restrict__ logits, __hip_bfloat16* __restrict__ x2h) {
  int b = blockIdx.x;
  int tid = threadIdx.x;
  int wave = tid >> 6, lane = tid & 63;
  const float* x1b = X1 + (size_t)b * SEQ * DIM;
  const float* x2b = X2 + (size_t)b * SEQ * DIM;
  __shared__ float sc[20];        // [0..9]=px, [10..19]=py
  __shared__ float4 xch[4 * 64];  // wave1 attx partial, lane-major
  if (tid == 0) logits[b] = 0.f;

  const float* Abase;
  const float* Brow;
  if (wave == 0)      { Abase = x1b;           Brow = x2b + 9 * DIM; }
  else if (wave == 1) { Abase = x1b + 5 * DIM; Brow = x2b + 9 * DIM; }
  else if (wave == 2) { Abase = x2b;           Brow = x1b + 9 * DIM; }
  else                { Abase = x2b + 5 * DIM; Brow = x1b + 9 * DIM; }

  float4 ra[5][4], rb[4];
#pragma unroll
  for (int i = 0; i < 4; i++)
    rb[i] = *(const float4*)(Brow + i * 256 + lane * 4);
#pragma unroll
  for (int s = 0; s < 5; s++)
#pragma unroll
    for (int i = 0; i < 4; i++)
      ra[s][i] = *(const float4*)(Abase + s * DIM + i * 256 + lane * 4);

  float v[5];
#pragma unroll
  for (int s = 0; s < 5; s++) {
    float4 a4 = ra[s][0] * rb[0] + ra[s][1] * rb[1] + ra[s][2] * rb[2] +
                ra[s][3] * rb[3];
    v[s] = a4.x + a4.y + a4.z + a4.w;
  }
#pragma unroll
  for (int off = 1; off < 64; off <<= 1)
#pragma unroll
    for (int s = 0; s < 5; s++) v[s] += __shfl_xor(v[s], off, 64);

  if (lane == 0) {
    int base = wave * 5;
    sc[base + 0] = v[0]; sc[base + 1] = v[1]; sc[base + 2] = v[2];
    sc[base + 3] = v[3]; sc[base + 4] = v[4];
  }
  __syncthreads();

  if (tid < SEQ) arow[(size_t)b * 16 + tid] = sc[10 + tid];

  // softmax over px (all threads redundantly; VALU is idle anyway)
  float px[SEQ];
#pragma unroll
  for (int s = 0; s < SEQ; s++) px[s] = sc[s];
  float m = -1e30f;
#pragma unroll
  for (int s = 0; s < SEQ; s++) m = fmaxf(m, px[s]);
  float w[SEQ], Z = 0.f;
#pragma unroll
  for (int s = 0; s < SEQ; s++) { w[s] = __expf(px[s] - m); Z += w[s]; }
  float inv = 1.f / Z;

  __hip_bfloat16* rowx1 = abf + (size_t)b * TWOD;            // [X1_9 | atty]
  __hip_bfloat16* rowx2 = abf + (size_t)(BATCH + b) * TWOD;  // [X2_9 | attx]

  if (wave == 1) {
#pragma unroll
    for (int i = 0; i < 4; i++) {
      float4 pb = ra[0][i] * w[5] + ra[1][i] * w[6] + ra[2][i] * w[7] +
                  ra[3][i] * w[8] + ra[4][i] * w[9];
      xch[i * 64 + lane] = pb;
      store_bf4(rowx2 + i * 256 + lane * 4, rb[i]);  // X2[b,9,:]
    }
  } else if (wave == 2) {
#pragma unroll
    for (int i = 0; i < 4; i++)
      store_bf4(rowx1 + i * 256 + lane * 4, rb[i]);  // X1[b,9,:]
  }
  __syncthreads();
  if (wave == 0) {
#pragma unroll
    for (int i = 0; i < 4; i++) {
      float4 ax = ra[0][i] * w[0] + ra[1][i] * w[1] + ra[2][i] * w[2] +
                  ra[3][i] * w[3] + ra[4][i] * w[4];
      ax = (ax + xch[i * 64 + lane]) * inv;
      store_bf4(rowx2 + DIM + i * 256 + lane * 4, ax);  // attx
    }
  } else if (x2h != nullptr && wave >= 2) {
    // dump register-held X2 rows as bf16 (overlaps wave0's attx work)
    __hip_bfloat16* dst = x2h + ((size_t)b * SEQ + (wave - 2) * 5) * DIM;
#pragma unroll
    for (int s = 0; s < 5; s++)
#pragma unroll
      for (int i = 0; i < 4; i++)
        store_bf4(dst + s * DIM + i * 256 + lane * 4, ra[s][i]);
  }
}

// P2: cross-batch softmax stats per t
__global__ __launch_bounds__(256) void k_stats(const float* __restrict__ arow,
                                               float* __restrict__ stats) {
  int t = blockIdx.x;
  int tid = threadIdx.x, lane = tid & 63, wave = tid >> 6;
  __shared__ float wred[4];
  float m = -1e30f;
  for (int b = tid; b < BATCH; b += 256) m = fmaxf(m, arow[(size_t)b * 16 + t]);
  for (int off = 32; off; off >>= 1) m = fmaxf(m, __shfl_down(m, off, 64));
  if (lane == 0) wred[wave] = m;
  __syncthreads();
  m = fmaxf(fmaxf(wred[0], wred[1]), fmaxf(wred[2], wred[3]));
  __syncthreads();
  float z = 0.f;
  for (int b = tid; b < BATCH; b += 256) z += __expf(arow[(size_t)b * 16 + t] - m);
  for (int off = 32; off; off >>= 1) z += __shfl_down(z, off, 64);
  if (lane == 0) wred[wave] = z;
  __syncthreads();
  if (tid == 0) {
    stats[t] = m;
    stats[16 + t] = wred[0] + wred[1] + wred[2] + wred[3];
  }
}

// P3 (bf16 path): atty[b,:] from x2h. 128 threads/block, 8 floats per thread.
__global__ __launch_bounds__(128) void k_apply_y_h(
    const __hip_bfloat16* __restrict__ x2h, const float* __restrict__ arow,
    const float* __restrict__ stats, __hip_bfloat16* __restrict__ abf) {
  int b = blockIdx.x;
  int tid = threadIdx.x;  // 0..127
  float wy[SEQ];
#pragma unroll
  for (int t = 0; t < SEQ; t++)
    wy[t] = __expf(arow[(size_t)b * 16 + t] - stats[t]) / stats[16 + t];
  const unsigned short* src =
      (const unsigned short*)x2h + (size_t)b * SEQ * DIM + tid * 8;
  float acc[8] = {};
#pragma unroll
  for (int t = 0; t < SEQ; t++) {
    ushort8_t vv = *(const ushort8_t*)(src + t * DIM);
#pragma unroll
    for (int j = 0; j < 8; j++) acc[j] += wy[t] * bf2f(vv[j]);
  }
  ushort8_t o;
#pragma unroll
  for (int j = 0; j < 8; j++) {
    __hip_bfloat16 h = __float2bfloat16(acc[j]);
    o[j] = *(unsigned short*)&h;
  }
  *(ushort8_t*)((unsigned short*)abf + (size_t)b * TWOD + DIM + tid * 8) = o;
}

// P3 (f32 fallback): as before.
__global__ __launch_bounds__(256) void k_apply_y(const float* __restrict__ X2,
                                                 const float* __restrict__ arow,
                                                 const float* __restrict__ stats,
                                                 __hip_bfloat16* __restrict__ abf) {
  int b = blockIdx.x;
  int wave = threadIdx.x >> 6, lane = threadIdx.x & 63;
  float wy[SEQ];
#pragma unroll
  for (int t = 0; t < SEQ; t++)
    wy[t] = __expf(arow[(size_t)b * 16 + t] - stats[t]) / stats[16 + t];
  const float* x2b = X2 + (size_t)b * SEQ * DIM;
  int d = wave * 256 + lane * 4;
  float4 acc = {0.f, 0.f, 0.f, 0.f};
#pragma unroll
  for (int t = 0; t < SEQ; t++)
    acc += wy[t] * *(const float4*)(x2b + t * DIM + d);
  store_bf4(abf + (size_t)b * TWOD + DIM + d, acc);
}

// Both weight transposes in one launch.
__global__ __launch_bounds__(256) void k_transpose_both(
    const float* __restrict__ Wg, const float* __restrict__ Wfd,
    __hip_bfloat16* __restrict__ wgt, __hip_bfloat16* __restrict__ wfdt) {
  __shared__ float t[32][33];
  int by = blockIdx.y;
  const float* in;
  __hip_bfloat16* out;
  int C, c0;
  if (by < 32) { in = Wg; out = wgt; C = DIM; c0 = by * 32; }
  else         { in = Wfd; out = wfdt; C = HID; c0 = (by - 32) * 32; }
  int r0 = blockIdx.x * 32;
  int tx = threadIdx.x & 31, ty = threadIdx.x >> 5;
#pragma unroll
  for (int i = 0; i < 4; i++)
    t[ty + 8 * i][tx] = in[(size_t)(r0 + ty + 8 * i) * C + c0 + tx];
  __syncthreads();
#pragma unroll
  for (int i = 0; i < 4; i++)
    out[(size_t)(c0 + ty + 8 * i) * TWOD + r0 + tx] =
        __float2bfloat16(t[tx][ty + 8 * i]);
}

// GEMM1: C[M,N]=A[M,K]@Bt[N,K]^T + bg. BM=128, BN=128, BK=64.
__global__ __launch_bounds__(256) void k_gemm1(
    const __hip_bfloat16* __restrict__ A, const __hip_bfloat16* __restrict__ Bt,
    const float* __restrict__ bias, __hip_bfloat16* __restrict__ outb, int K) {
  __shared__ short lds[16384];
  int tid = threadIdx.x;
  int lane = tid & 63, wave = tid >> 6;
  int m0 = blockIdx.y * 128, n0 = blockIdx.x * 128;
  int wr = wave >> 1, wc = wave & 1;

  f32x4 acc[4][4] = {};
  int lrow = lane >> 2, ls = lane & 3;
  int g = lane >> 4, r16 = lane & 15;

  for (int k0 = 0; k0 < K; k0 += 64) {
#pragma unroll
    for (int half = 0; half < 2; half++) {
      int kk = k0 + half * 32;
#pragma unroll
      for (int c = 0; c < 2; c++) {
        int R0 = 16 * (2 * wave + c);
        int rr = R0 + lrow;
        int slot = ls ^ SW(rr);
        GLOAD_LDS16(A + (size_t)(m0 + rr) * K + kk + slot * 8,
                    &lds[half * 4096 + R0 * 32]);
        GLOAD_LDS16(Bt + (size_t)(n0 + rr) * K + kk + slot * 8,
                    &lds[8192 + half * 4096 + R0 * 32]);
      }
    }
    __syncthreads();
#pragma unroll
    for (int half = 0; half < 2; half++) {
      bf16x8 af[4], bfr[4];
#pragma unroll
      for (int mi = 0; mi < 4; mi++) {
        int m = wr * 64 + mi * 16 + r16;
        af[mi] = *(const bf16x8*)&lds[half * 4096 + m * 32 + ((g ^ SW(m)) << 3)];
      }
#pragma unroll
      for (int ni = 0; ni < 4; ni++) {
        int n = wc * 64 + ni * 16 + r16;
        bfr[ni] =
            *(const bf16x8*)&lds[8192 + half * 4096 + n * 32 + ((g ^ SW(n)) << 3)];
      }
#pragma unroll
      for (int mi = 0; mi < 4; mi++)
#pragma unroll
        for (int ni = 0; ni < 4; ni++)
          acc[mi][ni] = __builtin_amdgcn_mfma_f32_16x16x32_bf16(
              af[mi], bfr[ni], acc[mi][ni], 0, 0, 0);
    }
    __syncthreads();
  }

#pragma unroll
  for (int mi = 0; mi < 4; mi++) {
#pragma unroll
    for (int ni = 0; ni < 4; ni++) {
#pragma unroll
      for (int r = 0; r < 4; r++) {
        int m = m0 + wr * 64 + mi * 16 + g * 4 + r;
        int n = n0 + wc * 64 + ni * 16 + r16;
        float v = acc[mi][ni][r] + bias[n];
        int om = m & (BATCH - 1);
        int on = n + ((m >> 12) << 10);
        outb[(size_t)om * TWOD + on] = __float2bfloat16(v);
      }
    }
  }
}

// GEMM2 fused with final dot: logits[m] += sum_n relu(oc@Wfd+bfd)[m,n]*Wff[n].
__global__ __launch_bounds__(256) void k_gemm2_final(
    const __hip_bfloat16* __restrict__ A, const __hip_bfloat16* __restrict__ Bt,
    const float* __restrict__ bfd, const float* __restrict__ Wff,
    float* __restrict__ logits, int K) {
  __shared__ short lds[12288];
  int tid = threadIdx.x;
  int lane = tid & 63, wave = tid >> 6;
  int m0 = blockIdx.y * 128, n0 = blockIdx.x * 64;
  int wr = wave >> 1, wc = wave & 1;

  f32x4 acc[4][2] = {};
  int lrow = lane >> 2, ls = lane & 3;
  int g = lane >> 4, r16 = lane & 15;

  for (int k0 = 0; k0 < K; k0 += 64) {
#pragma unroll
    for (int half = 0; half < 2; half++) {
      int kk = k0 + half * 32;
#pragma unroll
      for (int c = 0; c < 2; c++) {
        int R0 = 16 * (2 * wave + c);
        int rr = R0 + lrow;
        int slot = ls ^ SW(rr);
        GLOAD_LDS16(A + (size_t)(m0 + rr) * K + kk + slot * 8,
                    &lds[half * 4096 + R0 * 32]);
      }
      int RB = 16 * wave, rb = RB + lrow;
      int slotb = ls ^ SW(rb);
      GLOAD_LDS16(Bt + (size_t)(n0 + rb) * K + kk + slotb * 8,
                  &lds[8192 + half * 2048 + RB * 32]);
    }
    __syncthreads();
#pragma unroll
    for (int half = 0; half < 2; half++) {
      bf16x8 af[4], bfr[2];
#pragma unroll
      for (int mi = 0; mi < 4; mi++) {
        int m = wr * 64 + mi * 16 + r16;
        af[mi] = *(const bf16x8*)&lds[half * 4096 + m * 32 + ((g ^ SW(m)) << 3)];
      }
#pragma unroll
      for (int ni = 0; ni < 2; ni++) {
        int n = wc * 32 + ni * 16 + r16;
        bfr[ni] =
            *(const bf16x8*)&lds[8192 + half * 2048 + n * 32 + ((g ^ SW(n)) << 3)];
      }
#pragma unroll
      for (int mi = 0; mi < 4; mi++)
#pragma unroll
        for (int ni = 0; ni < 2; ni++)
          acc[mi][ni] = __builtin_amdgcn_mfma_f32_16x16x32_bf16(
              af[mi], bfr[ni], acc[mi][ni], 0, 0, 0);
    }
    __syncthreads();
  }

  int nA = n0 + wc * 32 + r16, nB = nA + 16;
  float bA = bfd[nA], bB = bfd[nB];
  float wA = Wff[nA], wB = Wff[nB];
#pragma unroll
  for (int mi = 0; mi < 4; mi++) {
#pragma unroll
    for (int r = 0; r < 4; r++) {
      float v0 = acc[mi][0][r] + bA; v0 = v0 > 0.f ? v0 : 0.f;
      float v1 = acc[mi][1][r] + bB; v1 = v1 > 0.f ? v1 : 0.f;
      float pl = v0 * wA + v1 * wB;
#pragma unroll
      for (int off = 1; off < 16; off <<= 1) pl += __shfl_xor(pl, off, 64);
      if (r16 == 0)
        atomicAdd(&logits[m0 + wr * 64 + mi * 16 + g * 4 + r], pl);
    }
  }
}

// out[b] = sigmoid(logits[b] + bff)
__global__ __launch_bounds__(256) void k_sigmoid(const float* __restrict__ logits,
                                                 const float* __restrict__ bff,
                                                 float* __restrict__ out) {
  int b = blockIdx.x * 256 + threadIdx.x;
  out[b] = 1.f / (1.f + __expf(-(logits[b] + bff[0])));
}

extern "C" void kernel_launch(void* const* d_in, const int* in_sizes, int n_in,
                              void* d_out, int out_size, void* d_ws, size_t ws_size,
                              hipStream_t stream) {
  const float* X1  = (const float*)d_in[0];
  const float* X2  = (const float*)d_in[1];
  const float* Wg  = (const float*)d_in[2];
  const float* bg  = (const float*)d_in[3];
  const float* Wfd = (const float*)d_in[4];
  const float* bfd = (const float*)d_in[5];
  const float* Wff = (const float*)d_in[6];
  const float* bff = (const float*)d_in[7];
  float* out = (float*)d_out;
  char* ws = (char*)d_ws;

  __hip_bfloat16* abf  = (__hip_bfloat16*)(ws + OFF_ABF);
  __hip_bfloat16* ocb  = (__hip_bfloat16*)(ws + OFF_OCB);
  __hip_bfloat16* wgt  = (__hip_bfloat16*)(ws + OFF_WGT);
  __hip_bfloat16* wfdt = (__hip_bfloat16*)(ws + OFF_WFDT);
  float* logits = (float*)(ws + OFF_LOG);
  float* arow   = (float*)(ws + OFF_AROW);
  float* stats  = (float*)(ws + OFF_STATS);
  __hip_bfloat16* x2h =
      (ws_size >= WS_NEED_X2H) ? (__hip_bfloat16*)(ws + OFF_X2H) : nullptr;

  k_transpose_both<<<dim3(64, 48), 256, 0, stream>>>(Wg, Wfd, wgt, wfdt);
  k_scores<<<BATCH, 256, 0, stream>>>(X1, X2, abf, arow, logits, x2h);
  k_stats<<<SEQ, 256, 0, stream>>>(arow, stats);
  if (x2h)
    k_apply_y_h<<<BATCH, 128, 0, stream>>>(x2h, arow, stats, abf);
  else
    k_apply_y<<<BATCH, 256, 0, stream>>>(X2, arow, stats, abf);
  // GEMM1: M=8192, N=1024, K=2048 -> ocb (bf16, remapped)
  k_gemm1<<<dim3(DIM / 128, 2 * BATCH / 128), 256, 0, stream>>>(
      abf, wgt, bg, ocb, TWOD);
  // GEMM2+final: M=4096, N=512, K=2048 -> logits
  k_gemm2_final<<<dim3(HID / 64, BATCH / 128), 256, 0, stream>>>(
      ocb, wfdt, bfd, Wff, logits, TWOD);
  k_sigmoid<<<BATCH / 256, 256, 0, stream>>>(logits, bff, out);
}